// Round 4
// baseline (1249.367 us; speedup 1.0000x reference)
//
#include <hip/hip_runtime.h>
#include <math.h>

// Problem constants
#define B_ 256
#define I_ 512
#define H_ 1024
#define M_ 128
#define A_ 2048
#define R_ 4
#define S_ 3
#define O_ 512
#define RS_ 512      // R*M
#define P_ 926       // R*(M+S+3) + 3*M+S+3
#define PW_OFF 536   // R*(M+S+3)
#define NP_ 1438     // 926 (Wint) ++ 512 (Wo_h) concatenated N
#define SK_ 4        // split-K factor for the two big GEMMs

typedef unsigned short ushort_t;
typedef __attribute__((ext_vector_type(8))) short bf16x8;
typedef __attribute__((ext_vector_type(4))) float f32x4;
typedef __attribute__((ext_vector_type(2))) float f32x2;
typedef __attribute__((ext_vector_type(4))) unsigned short u16x4;

__device__ __forceinline__ float sigmoidf_(float x) { return 1.0f / (1.0f + expf(-x)); }
__device__ __forceinline__ float softplusf_(float x) {
    return (x > 20.0f) ? x : log1pf(expf(x));
}
// f32 -> bf16 round-to-nearest-even
__device__ __forceinline__ ushort_t f2bf(float f) {
    unsigned int u = __float_as_uint(f);
    u = (u + 0x7FFFu + ((u >> 16) & 1u)) >> 16;
    return (ushort_t)u;
}

// sum of SK_ split-K partials of the p/oh GEMM (+ b_int bias), col < 926
__device__ __forceinline__ float pval(const float* __restrict__ pp,
                                      const float* __restrict__ b_int,
                                      int b, int col) {
    size_t o = (size_t)b * NP_ + col;
    size_t st = (size_t)B_ * NP_;
    return b_int[col] + pp[o] + pp[o + st] + pp[o + 2 * st] + pp[o + 3 * st];
}

// ---------------- block reductions (256 threads = 4 waves) ----------------
// Leading __syncthreads protects red[] from the previous reduction's reads.
__device__ __forceinline__ float bsum4(float v, float* red, int wv, int l) {
    #pragma unroll
    for (int off = 32; off; off >>= 1) v += __shfl_down(v, off, 64);
    __syncthreads();
    if (l == 0) red[wv] = v;
    __syncthreads();
    return red[0] + red[1] + red[2] + red[3];
}
__device__ __forceinline__ float bmax4(float v, float* red, int wv, int l) {
    #pragma unroll
    for (int off = 32; off; off >>= 1) v = fmaxf(v, __shfl_down(v, off, 64));
    __syncthreads();
    if (l == 0) red[wv] = v;
    __syncthreads();
    return fmaxf(fmaxf(red[0], red[1]), fmaxf(red[2], red[3]));
}

// ---------------- fused setup: 4 weight transposes + input prep + flags ----
// transpose+convert one 32x32 tile: WT[n][koff+k] = bf16(W[k][n])
__device__ __forceinline__ void transpose_tile(
    const float* __restrict__ W, ushort_t* __restrict__ WT,
    int K, int N, int ostride, int koff, int bx, int by, float (*tile)[33])
{
    int k0 = by * 32, n0 = bx * 32;
    int tx = threadIdx.x & 31, ty = threadIdx.x >> 5;  // ty 0..7
    #pragma unroll
    for (int i = 0; i < 4; ++i) {
        int k = ty + i * 8;
        int n = n0 + tx;
        float v = (n < N) ? W[(size_t)(k0 + k) * N + n] : 0.0f;
        tile[tx][k] = v;   // tile[n_local][k_local]
    }
    __syncthreads();
    #pragma unroll
    for (int i = 0; i < 4; ++i) {
        int nl = ty + i * 8;
        int n = n0 + nl;
        if (n < N) WT[(size_t)n * ostride + koff + k0 + tx] = f2bf(tile[nl][tx]);
    }
}

// region sizes: Wx 4096 | Wh 4096 | Wint 928 | Wo_h 512 | prep 2048 | flags 1
__global__ __launch_bounds__(256) void setup_kernel(
    const float* __restrict__ x, const float* __restrict__ rv,
    const float* __restrict__ hp,
    const float* __restrict__ Wx, const float* __restrict__ Wh,
    const float* __restrict__ Wint, const float* __restrict__ Wo_h,
    ushort_t* __restrict__ xin, ushort_t* __restrict__ WxhT,
    ushort_t* __restrict__ WpT, unsigned int* __restrict__ flags)
{
    __shared__ float tile[32][33];
    int r = blockIdx.x;
    if (r < 4096) { transpose_tile(Wx, WxhT, 1024, 4096, 2048, 0,    r % 128, r / 128, tile); return; }
    r -= 4096;
    if (r < 4096) { transpose_tile(Wh, WxhT, 1024, 4096, 2048, 1024, r % 128, r / 128, tile); return; }
    r -= 4096;
    if (r < 928)  { transpose_tile(Wint, WpT, 1024, 926, 1024, 0,    r % 29,  r / 29,  tile); return; }
    r -= 928;
    if (r < 512)  { transpose_tile(Wo_h, WpT + (size_t)926 * 1024, 1024, 512, 1024, 0, r % 16, r / 16, tile); return; }
    r -= 512;
    if (r < 2048) {
        // prep: xin_bf = bf16([x | read_vec_prev | h_prev])
        int idx = r * 256 + threadIdx.x;   // B*2048
        int b = idx >> 11, j = idx & 2047;
        float v;
        if (j < 512)       v = x[b * 512 + j];
        else if (j < 1024) v = rv[b * 512 + (j - 512)];
        else               v = hp[b * 1024 + (j - 1024)];
        xin[idx] = f2bf(v);
        return;
    }
    // flags zero (1 block, 256 threads)
    flags[threadIdx.x] = 0u;
}

// ---------------- bf16 MFMA GEMM, split-K partial output -------------------
// A: [M][lda] bf16; BT: [N][ldb] bf16 (W^T). blockIdx.z = split-K slice kz;
// each slice covers K range [kz*Ks, (kz+1)*Ks) and writes its own partial
// Cpart[kz][M][N] (f32, no bias). Consumers sum the SK_ partials.
template<bool NALIGN>
__global__ __launch_bounds__(256) void gemm_bf16_k(
    const ushort_t* __restrict__ A, int lda,
    const ushort_t* __restrict__ BT, int ldb,
    float* __restrict__ Cpart,
    int N, int Ks)
{
    __shared__ ushort_t As[64][40];   // pad 32->40 (80B rows: 2-way bank alias = free)
    __shared__ ushort_t Bs[64][40];
    int tid = threadIdx.x;
    int bm0 = blockIdx.y * 64, bn0 = blockIdx.x * 64;
    int kbeg = blockIdx.z * Ks, kend = kbeg + Ks;
    int srow = tid >> 2;              // staging: 64 rows x 4 threads x 8 elems
    int scol = (tid & 3) << 3;
    int wv = tid >> 6, l = tid & 63;
    int wm = (wv & 1) * 32, wn = (wv >> 1) * 32;
    int lane16 = l & 15, quad = l >> 4;

    f32x4 z4 = {0.0f, 0.0f, 0.0f, 0.0f};
    f32x4 acc00 = z4, acc01 = z4, acc10 = z4, acc11 = z4;

    const ushort_t* ap = A + (size_t)(bm0 + srow) * lda + scol;
    bool bvalid = NALIGN || (bn0 + srow) < N;
    const ushort_t* bp = BT + (size_t)(bn0 + srow) * ldb + scol;
    float4 fz = {0.0f, 0.0f, 0.0f, 0.0f};

    for (int k0 = kbeg; k0 < kend; k0 += 32) {
        *(float4*)&As[srow][scol] = *(const float4*)(ap + k0);
        if (bvalid) *(float4*)&Bs[srow][scol] = *(const float4*)(bp + k0);
        else        *(float4*)&Bs[srow][scol] = fz;
        __syncthreads();
        bf16x8 a0 = *(const bf16x8*)&As[wm + lane16][quad * 8];
        bf16x8 a1 = *(const bf16x8*)&As[wm + 16 + lane16][quad * 8];
        bf16x8 b0 = *(const bf16x8*)&Bs[wn + lane16][quad * 8];
        bf16x8 b1 = *(const bf16x8*)&Bs[wn + 16 + lane16][quad * 8];
        acc00 = __builtin_amdgcn_mfma_f32_16x16x32_bf16(a0, b0, acc00, 0, 0, 0);
        acc01 = __builtin_amdgcn_mfma_f32_16x16x32_bf16(a0, b1, acc01, 0, 0, 0);
        acc10 = __builtin_amdgcn_mfma_f32_16x16x32_bf16(a1, b0, acc10, 0, 0, 0);
        acc11 = __builtin_amdgcn_mfma_f32_16x16x32_bf16(a1, b1, acc11, 0, 0, 0);
        __syncthreads();
    }

    float* C = Cpart + (size_t)blockIdx.z * gridDim.y * 64 * N;
    // D layout: col = lane&15, row = quad*4 + reg
    #pragma unroll
    for (int gi = 0; gi < 2; ++gi) {
        #pragma unroll
        for (int gj = 0; gj < 2; ++gj) {
            const f32x4& acc = gi == 0 ? (gj == 0 ? acc00 : acc01)
                                       : (gj == 0 ? acc10 : acc11);
            int col = bn0 + wn + gj * 16 + lane16;
            if (NALIGN || col < N) {
                #pragma unroll
                for (int r2 = 0; r2 < 4; ++r2) {
                    int row = bm0 + wm + gi * 16 + quad * 4 + r2;
                    C[(size_t)row * N + col] = acc[r2];
                }
            }
        }
    }
}

// ---------------- LSTM gates (float4, sums 4 z-partials + bias) ------------
__global__ __launch_bounds__(256) void gates_kernel(
    const float* __restrict__ zpart, const float* __restrict__ b_lstm,
    const float* __restrict__ c_prev, ushort_t* __restrict__ h)
{
    int g = blockIdx.x * 256 + threadIdx.x;   // B*H/4 = 65536
    int b = g >> 8, j = (g & 255) << 2;
    size_t st = (size_t)B_ * 4096;
    size_t zb = (size_t)b * 4096 + j;
    f32x4 zs[4];
    #pragma unroll
    for (int q = 0; q < 4; ++q) {
        size_t o = zb + q * 1024;
        f32x4 v = *(const f32x4*)(zpart + o);
        v += *(const f32x4*)(zpart + o + st);
        v += *(const f32x4*)(zpart + o + 2 * st);
        v += *(const f32x4*)(zpart + o + 3 * st);
        v += *(const f32x4*)(b_lstm + q * 1024 + j);
        zs[q] = v;
    }
    f32x4 cp = *(const f32x4*)(c_prev + (size_t)b * 1024 + j);
    u16x4 hv;
    #pragma unroll
    for (int e = 0; e < 4; ++e) {
        float c = sigmoidf_(zs[1][e]) * cp[e] + sigmoidf_(zs[0][e]) * tanhf(zs[2][e]);
        hv[e] = f2bf(sigmoidf_(zs[3][e]) * tanhf(c));
    }
    *(u16x4*)(h + (size_t)b * 1024 + j) = hv;
}

// ---------------- mega2: sim + addressing + update + final, column-split ---
// Grid (4, B): 4 blocks per batch, each owns a 512-column quarter.
// 256 threads, ~29 KB LDS -> up to 5 blocks/CU resident; grid 1024 = 4/CU,
// so ALL blocks co-resident -> in-kernel rendezvous via device atomics safe.
// Phase 3 (addressing, full-A reductions) is recomputed redundantly per block
// from globally-shared dots/mn (only ~3 us of VALU).
__global__ __launch_bounds__(256) void mega2_kernel(
    const float* __restrict__ mem, const float* __restrict__ pohpart,
    const float* __restrict__ b_int,
    const float* __restrict__ read_w_prev, const float* __restrict__ write_w_prev,
    const float* __restrict__ Wout, const float* __restrict__ bo_h,
    const float* __restrict__ b_out,
    float* __restrict__ dots_g,        // [B][5][A]
    float* __restrict__ mn_g,          // [B][A]
    float* __restrict__ rvh_g,         // [4][B][RS]
    unsigned int* __restrict__ flags,  // [B]
    float* __restrict__ out,           // [B][O]
    float* __restrict__ mem_new)       // [B][M][A]
{
    int qb = blockIdx.x;               // column quarter 0..3
    int b  = blockIdx.y;
    int t = threadIdx.x;               // 0..255
    int wv = t >> 6, l = t & 63;       // 4 waves

    __shared__ float ks[5][M_];        // keys; reused as er/ad in phase 4
    __shared__ float w5[5][512];       // own-quarter head weights
    __shared__ float wg[A_];           // full gated weights (redundant ph3); rv in ph5
    __shared__ float rvp[M_][4][4];    // rv wave partials; reused as out partials
    __shared__ float red[4];

    // ---- phase 1: keys into LDS ----
    for (int idx = t; idx < 5 * M_; idx += 256) {
        int h = idx >> 7, m = idx & 127;
        int col = (h < 4) ? h * 134 + m : PW_OFF + m;
        ks[h][m] = pval(pohpart, b_int, b, col);
    }
    __syncthreads();

    // ---- phase 2: dots (5 heads) + column norms for own 2 columns ----
    int a0 = qb * 512 + 2 * t;
    {
        const float* mb = mem + (size_t)b * M_ * A_ + a0;
        f32x2 zz = {0.0f, 0.0f};
        f32x2 d0 = zz, d1 = zz, d2 = zz, d3 = zz, d4 = zz, nn = zz;
        for (int m = 0; m < M_; m += 8) {
            f32x2 vv[8];
            #pragma unroll
            for (int j = 0; j < 8; ++j)
                vv[j] = *(const f32x2*)(mb + (size_t)(m + j) * A_);
            #pragma unroll
            for (int j = 0; j < 8; ++j) {
                float k0 = ks[0][m + j], k1 = ks[1][m + j], k2 = ks[2][m + j];
                float k3 = ks[3][m + j], k4 = ks[4][m + j];
                #pragma unroll
                for (int c = 0; c < 2; ++c) {
                    float v = vv[j][c];
                    d0[c] += v * k0; d1[c] += v * k1; d2[c] += v * k2;
                    d3[c] += v * k3; d4[c] += v * k4;
                    nn[c] += v * v;
                }
            }
        }
        size_t base = (size_t)b * 5 * A_ + a0;
        *(f32x2*)(dots_g + base + 0 * A_) = d0;
        *(f32x2*)(dots_g + base + 1 * A_) = d1;
        *(f32x2*)(dots_g + base + 2 * A_) = d2;
        *(f32x2*)(dots_g + base + 3 * A_) = d3;
        *(f32x2*)(dots_g + base + 4 * A_) = d4;
        f32x2 rt = {sqrtf(nn[0]), sqrtf(nn[1])};
        *(f32x2*)(mn_g + (size_t)b * A_ + a0) = rt;
    }
    // ---- rendezvous 1: dots/mn of all 4 quarters visible ----
    __threadfence();
    __syncthreads();
    if (t == 0) {
        atomicAdd(&flags[b], 1u);
        int guard = 0;
        while (atomicAdd(&flags[b], 0u) < 4u && guard < (1 << 22)) {
            __builtin_amdgcn_s_sleep(2); ++guard;
        }
    }
    __syncthreads();
    __threadfence();

    // ---- phase 3: addressing per head, REDUNDANT full-A per block ----
    // thread owns full-A cols {4t..4t+3} and {1024+4t..1024+4t+3}
    for (int head = 0; head < 5; ++head) {
        int pb = (head < 4) ? head * 134 : PW_OFF;
        float beta  = softplusf_(pval(pohpart, b_int, b, pb + 128));
        float g     = sigmoidf_(pval(pohpart, b_int, b, pb + 129));
        float gamma = 1.0f + softplusf_(pval(pohpart, b_int, b, pb + 130));
        float e0 = pval(pohpart, b_int, b, pb + 131);
        float e1 = pval(pohpart, b_int, b, pb + 132);
        float e2 = pval(pohpart, b_int, b, pb + 133);
        float smax = fmaxf(e0, fmaxf(e1, e2));
        float x0 = __expf(e0 - smax), x1 = __expf(e1 - smax), x2 = __expf(e2 - smax);
        float sden = x0 + x1 + x2;
        float s0 = x0 / sden, s1 = x1 / sden, s2 = x2 / sden;

        float kacc = (t < M_) ? ks[head][t] * ks[head][t] : 0.0f;
        float kn = sqrtf(bsum4(kacc, red, wv, l));

        const float* db = dots_g + ((size_t)b * 5 + head) * A_;
        const float* mb = mn_g + (size_t)b * A_;
        f32x4 dA = *(const f32x4*)(db + 4 * t);
        f32x4 dB = *(const f32x4*)(db + 1024 + 4 * t);
        f32x4 mA = *(const f32x4*)(mb + 4 * t);
        f32x4 mB = *(const f32x4*)(mb + 1024 + 4 * t);
        f32x4 lA, lB;
        float lmax = -1e30f;
        #pragma unroll
        for (int c = 0; c < 4; ++c) {
            lA[c] = beta * dA[c] / (kn * mA[c] + 1e-8f);
            lB[c] = beta * dB[c] / (kn * mB[c] + 1e-8f);
            lmax = fmaxf(lmax, fmaxf(lA[c], lB[c]));
        }
        lmax = bmax4(lmax, red, wv, l);
        f32x4 eA, eB;
        float lsum = 0.0f;
        #pragma unroll
        for (int c = 0; c < 4; ++c) {
            eA[c] = __expf(lA[c] - lmax);
            eB[c] = __expf(lB[c] - lmax);
            lsum += eA[c] + eB[c];
        }
        lsum = bsum4(lsum, red, wv, l);
        float inv_lsum = 1.0f / lsum;

        const float* wprev = (head < 4) ? read_w_prev + ((size_t)b * 4 + head) * A_
                                        : write_w_prev + (size_t)b * A_;
        f32x4 pA = *(const f32x4*)(wprev + 4 * t);
        f32x4 pB = *(const f32x4*)(wprev + 1024 + 4 * t);
        f32x4 gA, gB;
        #pragma unroll
        for (int c = 0; c < 4; ++c) {
            gA[c] = g * (eA[c] * inv_lsum) + (1.0f - g) * pA[c];
            gB[c] = g * (eB[c] * inv_lsum) + (1.0f - g) * pB[c];
        }
        *(f32x4*)&wg[4 * t] = gA;
        *(f32x4*)&wg[1024 + 4 * t] = gB;
        __syncthreads();
        f32x4 wA, wB;
        float psum = 0.0f;
        #pragma unroll
        for (int c = 0; c < 4; ++c) {
            int a = 4 * t + c;
            float ws = s0 * wg[(a + 1) & (A_ - 1)] + s1 * wg[a] + s2 * wg[(a + A_ - 1) & (A_ - 1)];
            wA[c] = __expf(gamma * __logf(ws + 1e-12f));   // (ws+eps)^gamma
            a = 1024 + 4 * t + c;
            ws = s0 * wg[(a + 1) & (A_ - 1)] + s1 * wg[a] + s2 * wg[(a + A_ - 1) & (A_ - 1)];
            wB[c] = __expf(gamma * __logf(ws + 1e-12f));
            psum += wA[c] + wB[c];
        }
        psum = bsum4(psum, red, wv, l);   // syncs protect wg before next head
        float inv = 1.0f / (psum + 1e-8f);
        #pragma unroll
        for (int c = 0; c < 4; ++c) { wA[c] *= inv; wB[c] *= inv; }
        // keep only own-quarter slices in w5
        if ((t >> 7) == qb)
            *(f32x4*)&w5[head][4 * t - qb * 512] = wA;
        if ((t >> 7) == qb - 2)
            *(f32x4*)&w5[head][1024 + 4 * t - qb * 512] = wB;
    }
    // er/ad into ks (keys dead after last kn)
    if (t < M_)  ks[0][t] = sigmoidf_(pval(pohpart, b_int, b, 670 + t));
    else         ks[1][t - M_] = pval(pohpart, b_int, b, 798 + (t - M_));
    __syncthreads();

    // ---- phase 4: memory update + rv partials for own 2 columns ----
    {
        int lc = 2 * t;   // local col within quarter
        f32x2 ww = *(const f32x2*)&w5[4][lc];
        f32x2 w0 = *(const f32x2*)&w5[0][lc];
        f32x2 w1 = *(const f32x2*)&w5[1][lc];
        f32x2 w2 = *(const f32x2*)&w5[2][lc];
        f32x2 w3 = *(const f32x2*)&w5[3][lc];
        const float* mrow = mem + (size_t)b * M_ * A_ + a0;
        float* orow = mem_new + (size_t)b * M_ * A_ + a0;
        for (int m = 0; m < M_; m += 8) {
            f32x2 vv[8];
            #pragma unroll
            for (int j = 0; j < 8; ++j)
                vv[j] = *(const f32x2*)(mrow + (size_t)(m + j) * A_);
            #pragma unroll
            for (int j = 0; j < 8; ++j) {
                float er = ks[0][m + j], ad = ks[1][m + j];
                f32x2 ov;
                float s0a = 0, s1a = 0, s2a = 0, s3a = 0;
                #pragma unroll
                for (int c = 0; c < 2; ++c) {
                    float v = vv[j][c];
                    ov[c] = v * (1.0f - er * ww[c]) + ad * ww[c];
                    s0a += v * w0[c]; s1a += v * w1[c];
                    s2a += v * w2[c]; s3a += v * w3[c];
                }
                *(f32x2*)(orow + (size_t)(m + j) * A_) = ov;
                #pragma unroll
                for (int off = 32; off; off >>= 1) {
                    s0a += __shfl_down(s0a, off, 64);
                    s1a += __shfl_down(s1a, off, 64);
                    s2a += __shfl_down(s2a, off, 64);
                    s3a += __shfl_down(s3a, off, 64);
                }
                if (l == 0) {
                    rvp[m + j][wv][0] = s0a; rvp[m + j][wv][1] = s1a;
                    rvp[m + j][wv][2] = s2a; rvp[m + j][wv][3] = s3a;
                }
            }
        }
    }
    __syncthreads();
    // combine waves -> quarter rv partial to global
    for (int idx = t; idx < RS_; idx += 256) {
        int m = idx & 127, r = idx >> 7;
        float s = rvp[m][0][r] + rvp[m][1][r] + rvp[m][2][r] + rvp[m][3][r];
        rvh_g[((size_t)qb * B_ + b) * RS_ + r * M_ + m] = s;
    }
    // ---- rendezvous 2: all rv partials visible ----
    __threadfence();
    __syncthreads();
    if (t == 0) {
        atomicAdd(&flags[b], 1u);
        int guard = 0;
        while (atomicAdd(&flags[b], 0u) < 8u && guard < (1 << 22)) {
            __builtin_amdgcn_s_sleep(2); ++guard;
        }
    }
    __syncthreads();
    __threadfence();

    // full rv into wg[0..511]
    for (int k = t; k < RS_; k += 256) {
        float s = rvh_g[(size_t)b * RS_ + k]
                + rvh_g[((size_t)B_ + b) * RS_ + k]
                + rvh_g[((size_t)2 * B_ + b) * RS_ + k]
                + rvh_g[((size_t)3 * B_ + b) * RS_ + k];
        wg[k] = s;
    }
    __syncthreads();

    // ---- phase 5: out cols [qb*128, qb*128+128) = oh + biases + rv @ Wout --
    float* part = &rvp[0][0][0];       // 256 floats (rvp reads done above)
    {
        int kq = t >> 7;               // K half 0/1
        int oc = t & 127;
        int col = qb * 128 + oc;
        float acc = 0.0f;
        const float* wob = Wout + (size_t)kq * 256 * O_ + col;
        #pragma unroll 4
        for (int k = 0; k < 256; ++k)
            acc += wg[kq * 256 + k] * wob[(size_t)k * O_];
        part[t] = acc;
    }
    __syncthreads();
    if (t < 128) {
        int col = qb * 128 + t;
        size_t st = (size_t)B_ * NP_;
        size_t po = (size_t)b * NP_ + 926 + col;
        float oh = pohpart[po] + pohpart[po + st] + pohpart[po + 2 * st] + pohpart[po + 3 * st];
        out[(size_t)b * O_ + col] = part[t] + part[t + 128] + oh + bo_h[col] + b_out[col];
    }
}

extern "C" void kernel_launch(void* const* d_in, const int* in_sizes, int n_in,
                              void* d_out, int out_size, void* d_ws, size_t ws_size,
                              hipStream_t stream) {
    (void)in_sizes; (void)n_in; (void)out_size; (void)ws_size;
    const float* x            = (const float*)d_in[0];
    const float* h_prev       = (const float*)d_in[1];
    const float* c_prev       = (const float*)d_in[2];
    const float* read_w_prev  = (const float*)d_in[3];
    const float* write_w_prev = (const float*)d_in[4];
    const float* memory_prev  = (const float*)d_in[5];
    const float* read_vec_prev= (const float*)d_in[6];
    const float* Wx           = (const float*)d_in[7];
    const float* Wh           = (const float*)d_in[8];
    const float* b_lstm       = (const float*)d_in[9];
    const float* Wo_h         = (const float*)d_in[10];
    const float* bo_h         = (const float*)d_in[11];
    const float* Wint         = (const float*)d_in[12];
    const float* b_int        = (const float*)d_in[13];
    const float* Wout         = (const float*)d_in[14];
    const float* b_out        = (const float*)d_in[15];
    float* out = (float*)d_out;                  // [B*O] ++ [B*M*A]
    float* mem_new_out = out + (size_t)B_ * O_;

    char* wsp = (char*)d_ws;
    ushort_t* xin_bf = (ushort_t*)wsp; wsp += (size_t)B_ * 2048 * 2;          // 1 MB
    ushort_t* h_bf   = (ushort_t*)wsp; wsp += (size_t)B_ * H_ * 2;            // 0.5 MB
    ushort_t* WxhT   = (ushort_t*)wsp; wsp += (size_t)4096 * 2048 * 2;        // 16 MB
    ushort_t* WpT    = (ushort_t*)wsp; wsp += (size_t)NP_ * 1024 * 2;         // 2.94 MB
    float* zpart     = (float*)wsp;    wsp += (size_t)SK_ * B_ * 4096 * 4;    // 16 MB
    float* pohpart   = (float*)wsp;    wsp += (size_t)SK_ * B_ * NP_ * 4;     // 5.9 MB
    float* dots_g    = (float*)wsp;    wsp += (size_t)B_ * 5 * A_ * 4;        // 10.5 MB
    float* mn_g      = (float*)wsp;    wsp += (size_t)B_ * A_ * 4;            // 2 MB
    float* rvh_g     = (float*)wsp;    wsp += (size_t)4 * B_ * RS_ * 4;       // 2 MB
    unsigned int* flags = (unsigned int*)wsp; wsp += (size_t)B_ * 4;          // 1 KB

    // 1. setup: weight transposes (bf16) + xin prep + flag zero
    setup_kernel<<<dim3(4096 + 4096 + 928 + 512 + 2048 + 1), 256, 0, stream>>>(
        x, read_vec_prev, h_prev, Wx, Wh, Wint, Wo_h,
        xin_bf, WxhT, WpT, flags);
    // 2. z partials = xin @ [Wx;Wh]  (split-K=4: grid 1024 blocks = 4/CU)
    gemm_bf16_k<true><<<dim3(4096 / 64, B_ / 64, SK_), 256, 0, stream>>>(
        xin_bf, 2048, WxhT, 2048, zpart, 4096, 2048 / SK_);
    // 3. gates -> h (bf16); sums z partials + b_lstm
    gates_kernel<<<dim3(B_ * H_ / 1024), 256, 0, stream>>>(zpart, b_lstm, c_prev, h_bf);
    // 4. poh partials = h @ [Wint|Wo_h]  (N=1438, split-K=4: 368 blocks)
    gemm_bf16_k<false><<<dim3(23, B_ / 64, SK_), 256, 0, stream>>>(
        h_bf, 1024, WpT, 1024, pohpart, NP_, 1024 / SK_);
    // 5. mega2: sim + addressing + update + read-vec + final (column-split x4)
    mega2_kernel<<<dim3(4, B_), 256, 0, stream>>>(
        memory_prev, pohpart, b_int, read_w_prev, write_w_prev,
        Wout, bo_h, b_out, dots_g, mn_g, rvh_g, flags, out, mem_new_out);
}